// Round 3
// baseline (463.666 us; speedup 1.0000x reference)
//
#include <hip/hip_runtime.h>
#include <hip/hip_cooperative_groups.h>

namespace cg = cooperative_groups;

#define NBLK 512   // cooperative grid: 2 blocks/CU on 256 CUs
#define BT   256   // threads per block

// Shared memory reused across phases (separated by grid.sync()).
union SharedU {
    unsigned long long sk[512];                    // rank phase: staged keys
    struct {
        float U0[256], U1[256], C0[256], C1[256], C2[256];
        float A[256], CR[256], CG[256], CB[256];
        unsigned long long mask[4];
    } r;                                           // render phase
};

__global__ void __launch_bounds__(BT, 2) k_fused(
    const float* __restrict__ pws, const float* __restrict__ shs,
    const float* __restrict__ alphas_raw, const float* __restrict__ scales_raw,
    const float* __restrict__ rots_raw, const float* __restrict__ Rcw,
    const float* __restrict__ tcw, const float* __restrict__ intr,
    int N, int W, int H,
    float* __restrict__ out, float* __restrict__ areas,
    unsigned long long* __restrict__ keys, unsigned* __restrict__ rank,
    float* __restrict__ Pun, float* __restrict__ Pso,
    float4* __restrict__ cull, float4* __restrict__ seg1buf)
{
    cg::grid_group grid = cg::this_grid();
    __shared__ SharedU sh;
    const int b = blockIdx.x, tid = threadIdx.x;

    // ===================== Phase A: per-Gaussian preprocess =================
    // Block b handles Gaussians [b*per, b*per+per), lanes 0..per-1.
    {
        const int per = (N + NBLK - 1) / NBLK;   // 16 at N=8192
        const int i = b * per + tid;
        if (tid < per && i < N) {
            rank[i] = 0u;
            float R00=Rcw[0],R01=Rcw[1],R02=Rcw[2];
            float R10=Rcw[3],R11=Rcw[4],R12=Rcw[5];
            float R20=Rcw[6],R21=Rcw[7],R22=Rcw[8];
            float t0=tcw[0],t1=tcw[1],t2=tcw[2];
            float fx=intr[0],fy=intr[1],cx=intr[2],cy=intr[3];

            float pwx=pws[i*3+0], pwy=pws[i*3+1], pwz=pws[i*3+2];
            float pcx = R00*pwx + R01*pwy + R02*pwz + t0;
            float pcy = R10*pwx + R11*pwy + R12*pwz + t1;
            float pcz = R20*pwx + R21*pwy + R22*pwz + t2;
            float depth = pcz;
            float zs = (depth > 0.2f) ? depth : 1.0f;
            float u0 = fx * pcx / zs + cx;
            float u1 = fy * pcy / zs + cy;

            float qw=rots_raw[i*4+0], qx=rots_raw[i*4+1], qy=rots_raw[i*4+2], qz=rots_raw[i*4+3];
            float qn = sqrtf(qw*qw + qx*qx + qy*qy + qz*qz);
            qw/=qn; qx/=qn; qy/=qn; qz/=qn;
            float s0 = expf(scales_raw[i*3+0]);
            float s1 = expf(scales_raw[i*3+1]);
            float s2 = expf(scales_raw[i*3+2]);

            float xx=qx*qx, yy=qy*qy, zq=qz*qz;
            float xy=qx*qy, xz=qx*qz, yz=qy*qz;
            float wx=qw*qx, wy=qw*qy, wz=qw*qz;
            float r00=1.f-2.f*(yy+zq), r01=2.f*(xy-wz),     r02=2.f*(xz+wy);
            float r10=2.f*(xy+wz),     r11=1.f-2.f*(xx+zq), r12=2.f*(yz-wx);
            float r20=2.f*(xz-wy),     r21=2.f*(yz+wx),     r22=1.f-2.f*(xx+yy);

            float m00=r00*s0, m01=r01*s1, m02=r02*s2;
            float m10=r10*s0, m11=r11*s1, m12=r12*s2;
            float m20=r20*s0, m21=r21*s1, m22=r22*s2;
            float V00=m00*m00+m01*m01+m02*m02;
            float V01=m00*m10+m01*m11+m02*m12;
            float V02=m00*m20+m01*m21+m02*m22;
            float V11=m10*m10+m11*m11+m12*m12;
            float V12=m10*m20+m11*m21+m12*m22;
            float V22=m20*m20+m21*m21+m22*m22;

            float tanfx = (float)W / (2.f*fx), tanfy = (float)H / (2.f*fy);
            float limx = 1.3f*tanfx, limy = 1.3f*tanfy;
            float txl = fminf(fmaxf(pcx/zs, -limx), limx) * zs;
            float tyl = fminf(fmaxf(pcy/zs, -limy), limy) * zs;
            float iz = 1.f/zs, iz2 = iz*iz;
            float J00 = fx*iz, J02 = -fx*txl*iz2;
            float J11 = fy*iz, J12 = -fy*tyl*iz2;

            float T00=J00*R00+J02*R20, T01=J00*R01+J02*R21, T02=J00*R02+J02*R22;
            float T10=J11*R10+J12*R20, T11=J11*R11+J12*R21, T12=J11*R12+J12*R22;
            float A0=T00*V00+T01*V01+T02*V02;
            float A1=T00*V01+T01*V11+T02*V12;
            float A2=T00*V02+T01*V12+T02*V22;
            float B0=T10*V00+T11*V01+T12*V02;
            float B1=T10*V01+T11*V11+T12*V12;
            float B2=T10*V02+T11*V12+T12*V22;
            float ca = A0*T00+A1*T01+A2*T02 + 0.3f;
            float cb = A0*T10+A1*T11+A2*T12;
            float cc = B0*T10+B1*T11+B2*T12 + 0.3f;

            float det = ca*cc - cb*cb;
            bool valid = (depth > 0.2f) && (det > 0.f);
            float det_s = valid ? det : 1.f;
            float dinv = 1.f/det_s;
            float ci0 =  cc*dinv, ci1 = -cb*dinv, ci2 = ca*dinv;
            float mid = 0.5f*(ca+cc);
            float lam = mid + sqrtf(fmaxf(mid*mid - det, 0.1f));
            float radius = valid ? ceilf(3.f*sqrtf(lam)) : 0.f;
            areas[2*i+0] = radius;
            areas[2*i+1] = radius;

            float alpha = 1.f/(1.f + expf(-alphas_raw[i]));

            float tw0 = -(R00*t0 + R10*t1 + R20*t2);
            float tw1 = -(R01*t0 + R11*t1 + R21*t2);
            float tw2 = -(R02*t0 + R12*t1 + R22*t2);
            float dx_=pwx-tw0, dy_=pwy-tw1, dz_=pwz-tw2;
            float dn = sqrtf(dx_*dx_+dy_*dy_+dz_*dz_);
            float x=dx_/dn, y=dy_/dn, z=dz_/dn;
            float sxx=x*x, syy=y*y, szz=z*z;
            float sxy=x*y, syz=y*z, sxz=x*z;
            const float* shp = shs + i*48;
            float col[3];
            #pragma unroll
            for (int c = 0; c < 3; ++c) {
                float res = 0.28209479177387814f*shp[0*3+c];
                res += -0.4886025119029199f*y*shp[1*3+c]
                     +  0.4886025119029199f*z*shp[2*3+c]
                     + -0.4886025119029199f*x*shp[3*3+c];
                res +=  1.0925484305920792f*sxy*shp[4*3+c]
                     + -1.0925484305920792f*syz*shp[5*3+c]
                     +  0.31539156525252005f*(2.f*szz-sxx-syy)*shp[6*3+c]
                     + -1.0925484305920792f*sxz*shp[7*3+c]
                     +  0.5462742152960396f*(sxx-syy)*shp[8*3+c];
                res += -0.5900435899266435f*y*(3.f*sxx-syy)*shp[9*3+c]
                     +  2.890611442640554f*sxy*z*shp[10*3+c]
                     + -0.4570457994644658f*y*(4.f*szz-sxx-syy)*shp[11*3+c]
                     +  0.3731763325901154f*z*(2.f*szz-3.f*sxx-3.f*syy)*shp[12*3+c]
                     + -0.4570457994644658f*x*(4.f*szz-sxx-syy)*shp[13*3+c]
                     +  1.445305721320277f*z*(sxx-syy)*shp[14*3+c]
                     + -0.5900435899266435f*x*(sxx-3.f*syy)*shp[15*3+c];
                col[c] = fmaxf(res + 0.5f, 0.f);
            }

            float rc2;
            if (!valid || 255.f*alpha < 0.999f) {
                rc2 = -1.f;
            } else {
                float r2 = 2.f*lam*logf(255.f*alpha);
                float rr = sqrtf(fmaxf(r2, 0.f)) + 1.f;
                rc2 = rr*rr;
            }

            Pun[0*N+i]=u0;  Pun[1*N+i]=u1;  Pun[2*N+i]=ci0; Pun[3*N+i]=ci1;
            Pun[4*N+i]=ci2; Pun[5*N+i]=alpha; Pun[6*N+i]=col[0];
            Pun[7*N+i]=col[1]; Pun[8*N+i]=col[2]; Pun[9*N+i]=rc2;

            unsigned ud = __float_as_uint(depth);
            ud = (ud & 0x80000000u) ? ~ud : (ud | 0x80000000u);
            keys[i] = ((unsigned long long)ud << 32) | (unsigned)i;
        }
    }
    __threadfence();
    grid.sync();

    // ===================== Phase B: O(N^2) rank sort ========================
    // Keys unique => rank[i] = #{j: key[j] < key[i]} = stable argsort slot.
    {
        const int IC = (N + 255) >> 8;   // i-chunks of 256
        const int JCn = (N + 511) >> 9;  // j-chunks of 512
        if (b < IC * JCn) {
            const int ic = b % IC, jc = b / IC;
            const int j0 = jc << 9;
            for (int t = tid; t < 512; t += BT) {
                int j = j0 + t;
                sh.sk[t] = (j < N) ? keys[j] : ~0ull;
            }
            __syncthreads();
            const int i = (ic << 8) + tid;
            unsigned long long my = (i < N) ? keys[i] : 0ull;
            int c = 0;
            const ulonglong2* sk2 = (const ulonglong2*)sh.sk;
            #pragma unroll 8
            for (int t = 0; t < 256; ++t) {
                ulonglong2 kk = sk2[t];
                c += (kk.x < my) ? 1 : 0;
                c += (kk.y < my) ? 1 : 0;
            }
            if (i < N) atomicAdd(&rank[i], (unsigned)c);
        }
    }
    __threadfence();
    grid.sync();

    // ===================== Phase C: scatter into sorted order ===============
    {
        const int per = (N + NBLK - 1) / NBLK;
        const int i = b * per + tid;
        if (tid < per && i < N) {
            int s = (int)rank[i];
            cull[s] = make_float4(Pun[0*N+i], Pun[1*N+i], Pun[9*N+i], 0.f);
            Pso[0*N+s] = Pun[2*N+i];
            Pso[1*N+s] = Pun[3*N+i];
            Pso[2*N+s] = Pun[4*N+i];
            Pso[3*N+s] = Pun[5*N+i];
            Pso[4*N+s] = Pun[6*N+i];
            Pso[5*N+s] = Pun[7*N+i];
            Pso[6*N+s] = Pun[8*N+i];
        }
    }
    __threadfence();
    grid.sync();

    // ===================== Phase D: segmented tile render ===================
    // Block b: tile = b>>1, depth segment = b&1. Composition is associative:
    // C = C0 + T0*C1, so segments render independently with local T.
    const int tilesX = (W + 15) >> 4, tilesY = (H + 15) >> 4;
    const int nTiles = tilesX * tilesY;
    const int tile = b >> 1, seg = b & 1;
    const int half = (N + 1) >> 1;

    float T = 0.f, aR = 0.f, aG = 0.f, aB = 0.f;
    int pix = 0;
    bool inb = false;

    if (tile < nTiles) {
        const int tX = tile % tilesX, tY = tile / tilesX;
        const int ix = (tX << 4) + (tid & 15);
        const int iy = (tY << 4) + (tid >> 4);
        inb = (ix < W) && (iy < H);
        pix = inb ? (iy * W + ix) : 0;
        const float pxf = (float)ix, pyf = (float)iy;
        const float tx0 = (float)(tX << 4), ty0 = (float)(tY << 4);
        int tx1i = (tX << 4) + 15; if (tx1i > W-1) tx1i = W-1;
        int ty1i = (tY << 4) + 15; if (ty1i > H-1) ty1i = H-1;
        const float tx1 = (float)tx1i, ty1 = (float)ty1i;

        T = inb ? 1.f : 0.f;
        const int g0 = seg ? half : 0;
        const int g1 = seg ? N : half;
        const int wave = tid >> 6, lane = tid & 63;

        for (int base = g0; base < g1; base += BT) {
            int g = base + tid;
            bool ov = false;
            float u0=0.f,u1=0.f,c0=0.f,c1=0.f,c2=0.f,al=0.f,cr=0.f,cg=0.f,cbl=0.f;
            if (g < g1) {
                float4 cu = cull[g];
                u0 = cu.x; u1 = cu.y;
                float cxp = fminf(fmaxf(u0, tx0), tx1);
                float cyp = fminf(fmaxf(u1, ty0), ty1);
                float ddx = u0 - cxp, ddy = u1 - cyp;
                ov = (ddx*ddx + ddy*ddy) <= cu.z;
                if (ov) {
                    c0 = Pso[0*N+g]; c1 = Pso[1*N+g]; c2 = Pso[2*N+g]; al = Pso[3*N+g];
                    cr = Pso[4*N+g]; cg = Pso[5*N+g]; cbl = Pso[6*N+g];
                }
            }
            unsigned long long m = __ballot(ov);
            if (lane == 0) sh.r.mask[wave] = m;
            __syncthreads();
            int cnt = 0, off = 0;
            #pragma unroll
            for (int w2 = 0; w2 < 4; ++w2) {
                int pc = __popcll(sh.r.mask[w2]);
                if (w2 < wave) off += pc;
                cnt += pc;
            }
            if (ov) {
                int pos = off + __popcll(m & ((1ull << lane) - 1ull));
                sh.r.U0[pos]=u0; sh.r.U1[pos]=u1; sh.r.C0[pos]=c0;
                sh.r.C1[pos]=c1; sh.r.C2[pos]=c2; sh.r.A[pos]=al;
                sh.r.CR[pos]=cr; sh.r.CG[pos]=cg; sh.r.CB[pos]=cbl;
            }
            __syncthreads();

            for (int e = 0; e < cnt; ++e) {
                float gu0=sh.r.U0[e], gu1=sh.r.U1[e];
                float gc0=sh.r.C0[e], gc1=sh.r.C1[e], gc2=sh.r.C2[e];
                float ga=sh.r.A[e], gr=sh.r.CR[e], gg=sh.r.CG[e], gb=sh.r.CB[e];
                float ddx = pxf - gu0, ddy = pyf - gu1;
                float power = -0.5f*(gc0*ddx*ddx + gc2*ddy*ddy) - gc1*ddx*ddy;
                float alp = fminf(0.99f, ga * __expf(power));
                alp = (power <= 0.f && alp >= (1.0f/255.0f)) ? alp : 0.f;
                float w = (T > 0.0001f) ? alp * T : 0.f;
                aR = fmaf(w, gr, aR);
                aG = fmaf(w, gg, aG);
                aB = fmaf(w, gb, aB);
                T = T - T * alp;
            }
            int done = (T <= 0.0001f) ? 1 : 0;
            if (__syncthreads_and(done)) break;
        }

        if (seg == 1 && inb) seg1buf[pix] = make_float4(T, aR, aG, aB);
    }
    __threadfence();
    grid.sync();

    // ===================== Phase E: combine segments, store =================
    if (tile < nTiles && seg == 0 && inb) {
        float4 s1 = seg1buf[pix];
        const int HWp = W * H;
        out[pix]         = aR + T * s1.y;
        out[HWp + pix]   = aG + T * s1.z;
        out[2*HWp + pix] = aB + T * s1.w;
    }
}

// ---------------------------------------------------------------------------
extern "C" void kernel_launch(void* const* d_in, const int* in_sizes, int n_in,
                              void* d_out, int out_size, void* d_ws, size_t ws_size,
                              hipStream_t stream) {
    const float* pws        = (const float*)d_in[0];
    const float* shs        = (const float*)d_in[1];
    const float* alphas_raw = (const float*)d_in[2];
    const float* scales_raw = (const float*)d_in[3];
    const float* rots_raw   = (const float*)d_in[4];
    // d_in[5] = us (forward value cancels: u + us - us)
    const float* Rcw        = (const float*)d_in[6];
    const float* tcw        = (const float*)d_in[7];
    const float* intr       = (const float*)d_in[8];

    int N  = in_sizes[0] / 3;
    int HW = (out_size - 2 * N) / 3;
    int W = 1; while ((long long)W * W < (long long)HW) ++W;  // square image
    int H = HW / W;

    float* out   = (float*)d_out;
    float* areas = out + 3 * HW;

    // workspace carve-up (all offsets 16B-aligned at N=8192)
    char* ws = (char*)d_ws;
    unsigned long long* keys = (unsigned long long*)ws;             // N*8
    unsigned* rank = (unsigned*)(ws + (size_t)N * 8);               // N*4
    float* Pun = (float*)(ws + (size_t)N * 12);                     // 10N*4
    float* Pso = Pun + (size_t)10 * N;                              // 7N*4
    float4* cullv = (float4*)(Pso + (size_t)7 * N);                 // N*16
    float4* seg1buf = cullv + N;                                    // HW*16

    void* args[] = {
        (void*)&pws, (void*)&shs, (void*)&alphas_raw, (void*)&scales_raw,
        (void*)&rots_raw, (void*)&Rcw, (void*)&tcw, (void*)&intr,
        (void*)&N, (void*)&W, (void*)&H,
        (void*)&out, (void*)&areas,
        (void*)&keys, (void*)&rank, (void*)&Pun, (void*)&Pso,
        (void*)&cullv, (void*)&seg1buf
    };
    hipLaunchCooperativeKernel((const void*)k_fused, dim3(NBLK), dim3(BT),
                               args, 0, stream);
}

// Round 4
// 109.192 us; speedup vs baseline: 4.2464x; 4.2464x over previous
//
#include <hip/hip_runtime.h>

// ---------------------------------------------------------------------------
// Kernel 1: per-Gaussian preprocessing. Writes areas, unsorted param SoA,
// depth sort keys, zero-inits rank.
// ---------------------------------------------------------------------------
__global__ __launch_bounds__(256) void k_pre(
    const float* __restrict__ pws, const float* __restrict__ shs,
    const float* __restrict__ alphas_raw, const float* __restrict__ scales_raw,
    const float* __restrict__ rots_raw, const float* __restrict__ Rcw,
    const float* __restrict__ tcw, const float* __restrict__ intr,
    int N, int W, int H, float* __restrict__ areas,
    unsigned long long* __restrict__ keys, unsigned* __restrict__ rank,
    float* __restrict__ P)
{
    int i = blockIdx.x * 256 + threadIdx.x;
    if (i >= N) return;
    rank[i] = 0u;

    float R00=Rcw[0],R01=Rcw[1],R02=Rcw[2];
    float R10=Rcw[3],R11=Rcw[4],R12=Rcw[5];
    float R20=Rcw[6],R21=Rcw[7],R22=Rcw[8];
    float t0=tcw[0],t1=tcw[1],t2=tcw[2];
    float fx=intr[0],fy=intr[1],cx=intr[2],cy=intr[3];

    float pwx=pws[i*3+0], pwy=pws[i*3+1], pwz=pws[i*3+2];
    float pcx = R00*pwx + R01*pwy + R02*pwz + t0;
    float pcy = R10*pwx + R11*pwy + R12*pwz + t1;
    float pcz = R20*pwx + R21*pwy + R22*pwz + t2;
    float depth = pcz;
    float zs = (depth > 0.2f) ? depth : 1.0f;
    float u0 = fx * pcx / zs + cx;
    float u1 = fy * pcy / zs + cy;

    float qw=rots_raw[i*4+0], qx=rots_raw[i*4+1], qy=rots_raw[i*4+2], qz=rots_raw[i*4+3];
    float qn = sqrtf(qw*qw + qx*qx + qy*qy + qz*qz);
    qw/=qn; qx/=qn; qy/=qn; qz/=qn;
    float s0 = expf(scales_raw[i*3+0]);
    float s1 = expf(scales_raw[i*3+1]);
    float s2 = expf(scales_raw[i*3+2]);

    float xx=qx*qx, yy=qy*qy, zq=qz*qz;
    float xy=qx*qy, xz=qx*qz, yz=qy*qz;
    float wx=qw*qx, wy=qw*qy, wz=qw*qz;
    float r00=1.f-2.f*(yy+zq), r01=2.f*(xy-wz),     r02=2.f*(xz+wy);
    float r10=2.f*(xy+wz),     r11=1.f-2.f*(xx+zq), r12=2.f*(yz-wx);
    float r20=2.f*(xz-wy),     r21=2.f*(yz+wx),     r22=1.f-2.f*(xx+yy);

    float m00=r00*s0, m01=r01*s1, m02=r02*s2;
    float m10=r10*s0, m11=r11*s1, m12=r12*s2;
    float m20=r20*s0, m21=r21*s1, m22=r22*s2;
    float V00=m00*m00+m01*m01+m02*m02;
    float V01=m00*m10+m01*m11+m02*m12;
    float V02=m00*m20+m01*m21+m02*m22;
    float V11=m10*m10+m11*m11+m12*m12;
    float V12=m10*m20+m11*m21+m12*m22;
    float V22=m20*m20+m21*m21+m22*m22;

    float tanfx = (float)W / (2.f*fx), tanfy = (float)H / (2.f*fy);
    float limx = 1.3f*tanfx, limy = 1.3f*tanfy;
    float txl = fminf(fmaxf(pcx/zs, -limx), limx) * zs;
    float tyl = fminf(fmaxf(pcy/zs, -limy), limy) * zs;
    float iz = 1.f/zs, iz2 = iz*iz;
    float J00 = fx*iz, J02 = -fx*txl*iz2;
    float J11 = fy*iz, J12 = -fy*tyl*iz2;

    float T00=J00*R00+J02*R20, T01=J00*R01+J02*R21, T02=J00*R02+J02*R22;
    float T10=J11*R10+J12*R20, T11=J11*R11+J12*R21, T12=J11*R12+J12*R22;
    float A0=T00*V00+T01*V01+T02*V02;
    float A1=T00*V01+T01*V11+T02*V12;
    float A2=T00*V02+T01*V12+T02*V22;
    float B0=T10*V00+T11*V01+T12*V02;
    float B1=T10*V01+T11*V11+T12*V12;
    float B2=T10*V02+T11*V12+T12*V22;
    float ca = A0*T00+A1*T01+A2*T02 + 0.3f;
    float cb = A0*T10+A1*T11+A2*T12;
    float cc = B0*T10+B1*T11+B2*T12 + 0.3f;

    float det = ca*cc - cb*cb;
    bool valid = (depth > 0.2f) && (det > 0.f);
    float det_s = valid ? det : 1.f;
    float dinv = 1.f/det_s;
    float ci0 =  cc*dinv, ci1 = -cb*dinv, ci2 = ca*dinv;
    float mid = 0.5f*(ca+cc);
    float lam = mid + sqrtf(fmaxf(mid*mid - det, 0.1f));
    float radius = valid ? ceilf(3.f*sqrtf(lam)) : 0.f;
    areas[2*i+0] = radius;
    areas[2*i+1] = radius;

    float alpha = 1.f/(1.f + expf(-alphas_raw[i]));

    float tw0 = -(R00*t0 + R10*t1 + R20*t2);
    float tw1 = -(R01*t0 + R11*t1 + R21*t2);
    float tw2 = -(R02*t0 + R12*t1 + R22*t2);
    float dx_=pwx-tw0, dy_=pwy-tw1, dz_=pwz-tw2;
    float dn = sqrtf(dx_*dx_+dy_*dy_+dz_*dz_);
    float x=dx_/dn, y=dy_/dn, z=dz_/dn;
    float sxx=x*x, syy=y*y, szz=z*z;
    float sxy=x*y, syz=y*z, sxz=x*z;
    const float* sh = shs + i*48;
    float col[3];
    #pragma unroll
    for (int c = 0; c < 3; ++c) {
        float res = 0.28209479177387814f*sh[0*3+c];
        res += -0.4886025119029199f*y*sh[1*3+c]
             +  0.4886025119029199f*z*sh[2*3+c]
             + -0.4886025119029199f*x*sh[3*3+c];
        res +=  1.0925484305920792f*sxy*sh[4*3+c]
             + -1.0925484305920792f*syz*sh[5*3+c]
             +  0.31539156525252005f*(2.f*szz-sxx-syy)*sh[6*3+c]
             + -1.0925484305920792f*sxz*sh[7*3+c]
             +  0.5462742152960396f*(sxx-syy)*sh[8*3+c];
        res += -0.5900435899266435f*y*(3.f*sxx-syy)*sh[9*3+c]
             +  2.890611442640554f*sxy*z*sh[10*3+c]
             + -0.4570457994644658f*y*(4.f*szz-sxx-syy)*sh[11*3+c]
             +  0.3731763325901154f*z*(2.f*szz-3.f*sxx-3.f*syy)*sh[12*3+c]
             + -0.4570457994644658f*x*(4.f*szz-sxx-syy)*sh[13*3+c]
             +  1.445305721320277f*z*(sxx-syy)*sh[14*3+c]
             + -0.5900435899266435f*x*(sxx-3.f*syy)*sh[15*3+c];
        col[c] = fmaxf(res + 0.5f, 0.f);
    }

    float rc2;
    if (!valid || 255.f*alpha < 0.999f) {
        rc2 = -1.f;
    } else {
        float r2 = 2.f*lam*logf(255.f*alpha);
        float r  = sqrtf(fmaxf(r2, 0.f)) + 1.f;
        rc2 = r*r;
    }

    P[0*N+i]=u0;  P[1*N+i]=u1;  P[2*N+i]=ci0; P[3*N+i]=ci1; P[4*N+i]=ci2;
    P[5*N+i]=alpha; P[6*N+i]=col[0]; P[7*N+i]=col[1]; P[8*N+i]=col[2];
    P[9*N+i]=rc2;

    unsigned ud = __float_as_uint(depth);
    ud = (ud & 0x80000000u) ? ~ud : (ud | 0x80000000u);
    keys[i] = ((unsigned long long)ud << 32) | (unsigned)i;
}

// ---------------------------------------------------------------------------
// Kernel 2: O(N^2) rank sort (unique keys => rank == stable argsort slot).
// ---------------------------------------------------------------------------
#define JC 512
__global__ __launch_bounds__(256) void k_rank(
    const unsigned long long* __restrict__ keys, int N,
    unsigned* __restrict__ rank)
{
    __shared__ unsigned long long sk[JC];
    const int j0 = blockIdx.y * JC;
    for (int t = threadIdx.x; t < JC; t += 256) {
        int j = j0 + t;
        sk[t] = (j < N) ? keys[j] : ~0ull;
    }
    __syncthreads();

    const int i0 = blockIdx.x * 512 + threadIdx.x;
    const int i1 = i0 + 256;
    unsigned long long my0 = (i0 < N) ? keys[i0] : 0ull;
    unsigned long long my1 = (i1 < N) ? keys[i1] : 0ull;

    int c0 = 0, c1 = 0;
    const ulonglong2* sk2 = (const ulonglong2*)sk;
    #pragma unroll 4
    for (int t = 0; t < JC/2; ++t) {
        ulonglong2 kk = sk2[t];
        c0 += (kk.x < my0) ? 1 : 0;
        c0 += (kk.y < my0) ? 1 : 0;
        c1 += (kk.x < my1) ? 1 : 0;
        c1 += (kk.y < my1) ? 1 : 0;
    }
    if (i0 < N) atomicAdd(&rank[i0], (unsigned)c0);
    if (i1 < N) atomicAdd(&rank[i1], (unsigned)c1);
}

// ---------------------------------------------------------------------------
// Kernel 3: scatter into sorted order, float4-packed for the render:
//   cull[s] = (u0,u1,rc2,0); gA[s] = (ci0,ci1,ci2,alpha); gB[s] = (r,g,b,0)
// ---------------------------------------------------------------------------
__global__ __launch_bounds__(256) void k_scatter(
    const unsigned* __restrict__ rank, const float* __restrict__ Pun,
    float4* __restrict__ gA, float4* __restrict__ gB,
    float4* __restrict__ cull, int N)
{
    int i = blockIdx.x * 256 + threadIdx.x;
    if (i >= N) return;
    int s = (int)rank[i];
    cull[s] = make_float4(Pun[0*N+i], Pun[1*N+i], Pun[9*N+i], 0.f);
    gA[s]   = make_float4(Pun[2*N+i], Pun[3*N+i], Pun[4*N+i], Pun[5*N+i]);
    gB[s]   = make_float4(Pun[6*N+i], Pun[7*N+i], Pun[8*N+i], 0.f);
}

// ---------------------------------------------------------------------------
// Kernel 4: segmented tile render. Grid = nTiles * nseg blocks; block b
// renders tile (b % nTiles), depth segment (b / nTiles) with LOCAL
// transmittance into segbuf[seg*HW + pix] = (T, R, G, B).
// Associativity: C = C0 + T0*C1; local 1e-4 cutoff error <= ~1e-4 (global
// T <= local T always, so anything we zero the reference zeroes too).
// ---------------------------------------------------------------------------
__global__ __launch_bounds__(256) void k_render(
    const float4* __restrict__ gA, const float4* __restrict__ gB,
    const float4* __restrict__ cull, int N, int W, int H,
    int nTiles, int nseg, float4* __restrict__ segbuf)
{
    const int tid = threadIdx.x;
    const int tilesX = (W + 15) >> 4;
    const int tile = blockIdx.x % nTiles, seg = blockIdx.x / nTiles;
    const int tX = tile % tilesX, tY = tile / tilesX;
    const int ix = (tX << 4) + (tid & 15);
    const int iy = (tY << 4) + (tid >> 4);
    const bool inb = (ix < W) && (iy < H);
    const float pxf = (float)ix, pyf = (float)iy;
    const float tx0 = (float)(tX << 4), ty0 = (float)(tY << 4);
    int tx1i = (tX << 4) + 15; if (tx1i > W-1) tx1i = W-1;
    int ty1i = (tY << 4) + 15; if (ty1i > H-1) ty1i = H-1;
    const float tx1 = (float)tx1i, ty1 = (float)ty1i;

    const int per = (N + nseg - 1) / nseg;
    const int g0 = seg * per;
    const int g1 = min(N, g0 + per);

    float T = inb ? 1.f : 0.f;
    float aR = 0.f, aG = 0.f, aB = 0.f;

    __shared__ float4 sG0[256];   // u0,u1,ci0,ci1
    __shared__ float4 sG1[256];   // ci2,alpha,r,g
    __shared__ float  sB2[256];   // b
    __shared__ unsigned long long sMask[4];

    const int wave = tid >> 6, lane = tid & 63;

    for (int base = g0; base < g1; base += 256) {
        int g = base + tid;
        bool ov = false;
        float u0=0.f, u1=0.f;
        float4 a4 = make_float4(0.f,0.f,0.f,0.f);
        float4 b4 = make_float4(0.f,0.f,0.f,0.f);
        if (g < g1) {
            float4 cu = cull[g];
            u0 = cu.x; u1 = cu.y;
            float cxp = fminf(fmaxf(u0, tx0), tx1);
            float cyp = fminf(fmaxf(u1, ty0), ty1);
            float ddx = u0 - cxp, ddy = u1 - cyp;
            ov = (ddx*ddx + ddy*ddy) <= cu.z;
            if (ov) { a4 = gA[g]; b4 = gB[g]; }
        }
        unsigned long long m = __ballot(ov);
        if (lane == 0) sMask[wave] = m;
        __syncthreads();
        int cnt = 0, off = 0;
        #pragma unroll
        for (int w2 = 0; w2 < 4; ++w2) {
            int pc = __popcll(sMask[w2]);
            if (w2 < wave) off += pc;
            cnt += pc;
        }
        if (ov) {
            int pos = off + __popcll(m & ((1ull << lane) - 1ull));
            sG0[pos] = make_float4(u0, u1, a4.x, a4.y);
            sG1[pos] = make_float4(a4.z, a4.w, b4.x, b4.y);
            sB2[pos] = b4.z;
        }
        __syncthreads();

        for (int e = 0; e < cnt; ++e) {
            float4 e0 = sG0[e];
            float4 e1 = sG1[e];
            float  gb = sB2[e];
            float ddx = pxf - e0.x, ddy = pyf - e0.y;
            float power = -0.5f*(e0.z*ddx*ddx + e1.x*ddy*ddy) - e0.w*ddx*ddy;
            float alp = fminf(0.99f, e1.y * __expf(power));
            alp = (power <= 0.f && alp >= (1.0f/255.0f)) ? alp : 0.f;
            float w = (T > 0.0001f) ? alp * T : 0.f;
            aR = fmaf(w, e1.z, aR);
            aG = fmaf(w, e1.w, aG);
            aB = fmaf(w, gb, aB);
            T = T - T * alp;
        }
        int done = (T <= 0.0001f) ? 1 : 0;
        if (__syncthreads_and(done)) break;
    }

    if (inb) {
        int pix = iy * W + ix;
        segbuf[(size_t)seg * (size_t)(W*H) + pix] = make_float4(T, aR, aG, aB);
    }
}

// ---------------------------------------------------------------------------
// Kernel 5: combine depth segments front-to-back.
// ---------------------------------------------------------------------------
__global__ __launch_bounds__(256) void k_combine(
    const float4* __restrict__ segbuf, int HW, int nseg,
    float* __restrict__ out)
{
    int p = blockIdx.x * 256 + threadIdx.x;
    if (p >= HW) return;
    float T = 1.f, r = 0.f, g = 0.f, b = 0.f;
    for (int s = 0; s < nseg; ++s) {
        float4 v = segbuf[(size_t)s * HW + p];
        r = fmaf(T, v.y, r);
        g = fmaf(T, v.z, g);
        b = fmaf(T, v.w, b);
        T *= v.x;
    }
    out[p] = r; out[HW + p] = g; out[2*HW + p] = b;
}

// ---------------------------------------------------------------------------
extern "C" void kernel_launch(void* const* d_in, const int* in_sizes, int n_in,
                              void* d_out, int out_size, void* d_ws, size_t ws_size,
                              hipStream_t stream) {
    const float* pws        = (const float*)d_in[0];
    const float* shs        = (const float*)d_in[1];
    const float* alphas_raw = (const float*)d_in[2];
    const float* scales_raw = (const float*)d_in[3];
    const float* rots_raw   = (const float*)d_in[4];
    // d_in[5] = us (forward value cancels: u + us - us)
    const float* Rcw        = (const float*)d_in[6];
    const float* tcw        = (const float*)d_in[7];
    const float* intr       = (const float*)d_in[8];

    const int N  = in_sizes[0] / 3;
    const int HW = (out_size - 2 * N) / 3;
    int W = 1; while ((long long)W * W < (long long)HW) ++W;  // square image
    const int H = HW / W;

    float* out   = (float*)d_out;
    float* areas = out + 3 * HW;

    // workspace carve-up (16B-aligned pieces)
    char* ws = (char*)d_ws;
    size_t off = 0;
    unsigned long long* keys = (unsigned long long*)(ws + off); off += (size_t)N * 8;
    unsigned* rank = (unsigned*)(ws + off);                     off += (size_t)N * 4;
    off = (off + 15) & ~(size_t)15;
    float* Pun = (float*)(ws + off);                            off += (size_t)10 * N * 4;
    off = (off + 15) & ~(size_t)15;
    float4* cullv = (float4*)(ws + off);                        off += (size_t)N * 16;
    float4* gA = (float4*)(ws + off);                           off += (size_t)N * 16;
    float4* gB = (float4*)(ws + off);                           off += (size_t)N * 16;
    float4* segbuf = (float4*)(ws + off);
    size_t remain = (ws_size > off) ? (ws_size - off) : 0;
    int nseg = 4;
    while (nseg > 1 && (size_t)nseg * (size_t)HW * 16 > remain) nseg >>= 1;

    int gsN = (N + 255) / 256;
    k_pre<<<gsN, 256, 0, stream>>>(pws, shs, alphas_raw, scales_raw, rots_raw,
                                   Rcw, tcw, intr, N, W, H, areas, keys, rank, Pun);
    dim3 rgrid((N + 511) / 512, (N + JC - 1) / JC);
    k_rank<<<rgrid, 256, 0, stream>>>(keys, N, rank);
    k_scatter<<<gsN, 256, 0, stream>>>(rank, Pun, gA, gB, cullv, N);
    int tilesX = (W + 15) / 16, tilesY = (H + 15) / 16;
    int nTiles = tilesX * tilesY;
    k_render<<<nTiles * nseg, 256, 0, stream>>>(gA, gB, cullv, N, W, H,
                                                nTiles, nseg, segbuf);
    k_combine<<<(HW + 255) / 256, 256, 0, stream>>>(segbuf, HW, nseg, out);
}